// Round 1
// baseline (1593.783 us; speedup 1.0000x reference)
//
#include <hip/hip_runtime.h>
#include <hip/hip_bf16.h>

// GraphSage: h1 = segsum(val * x[dst] -> src) / deg; out = [x, h1] @ W
// N=50000, D=128, E=800000, W is [256,128] fp32, out [N,128] fp32.

#define N_NODES 50000
#define DIM 128
#define N_EDGES 800000

// ---------------------------------------------------------------------------
// Kernel 1: edge scatter with atomics.
// 32 threads per edge; each thread handles 4 consecutive features (float4).
// lane (t&31)==0 also accumulates the degree.
// ---------------------------------------------------------------------------
__global__ __launch_bounds__(256) void scatter_kernel(
    const float* __restrict__ x,
    const int* __restrict__ esrc,
    const int* __restrict__ edst,
    const float* __restrict__ eval,
    float* __restrict__ h1,
    float* __restrict__ deg)
{
    long long t = (long long)blockIdx.x * blockDim.x + threadIdx.x;
    int e = (int)(t >> 5);            // edge index (32 threads per edge)
    if (e >= N_EDGES) return;
    int dq = ((int)t & 31) << 2;      // feature offset: 0,4,...,124

    int src = esrc[e];
    int dst = edst[e];
    float v = eval[e];

    const float4 xv = *reinterpret_cast<const float4*>(x + (long long)dst * DIM + dq);
    float* hrow = h1 + (long long)src * DIM + dq;
    atomicAdd(hrow + 0, v * xv.x);
    atomicAdd(hrow + 1, v * xv.y);
    atomicAdd(hrow + 2, v * xv.z);
    atomicAdd(hrow + 3, v * xv.w);

    if ((t & 31) == 0) {
        atomicAdd(deg + src, v);
    }
}

// ---------------------------------------------------------------------------
// Kernel 2: fused normalize + concat + matmul.
// One block (128 threads) per node row. Stage x-row and normalized h1-row in
// LDS, then each thread j computes out[i][j] = sum_d xs[d]*W[d][j]
//                                            + sum_d hs[d]*W[128+d][j].
// W column reads are coalesced across threads (consecutive j).
// ---------------------------------------------------------------------------
__global__ __launch_bounds__(128) void mm_kernel(
    const float* __restrict__ x,
    const float* __restrict__ h1,
    const float* __restrict__ deg,
    const float* __restrict__ W,
    float* __restrict__ out)
{
    __shared__ float xs[DIM];
    __shared__ float hs[DIM];

    int i = blockIdx.x;
    int j = threadIdx.x;

    long long row = (long long)i * DIM;
    xs[j] = x[row + j];
    float d = deg[i];
    hs[j] = h1[row + j] / (d + 1e-6f);
    __syncthreads();

    float acc = 0.0f;
    #pragma unroll
    for (int k = 0; k < DIM; ++k) {
        acc += xs[k] * W[k * DIM + j];
    }
    #pragma unroll
    for (int k = 0; k < DIM; ++k) {
        acc += hs[k] * W[(DIM + k) * DIM + j];
    }
    out[row + j] = acc;
}

extern "C" void kernel_launch(void* const* d_in, const int* in_sizes, int n_in,
                              void* d_out, int out_size, void* d_ws, size_t ws_size,
                              hipStream_t stream) {
    const float* x    = (const float*)d_in[0];
    const float* W    = (const float*)d_in[1];
    const int*   esrc = (const int*)d_in[2];
    const int*   edst = (const int*)d_in[3];
    const float* eval = (const float*)d_in[4];
    float* out = (float*)d_out;

    float* h1  = (float*)d_ws;                       // N*D floats
    float* deg = h1 + (size_t)N_NODES * DIM;         // N floats

    size_t zero_bytes = ((size_t)N_NODES * DIM + N_NODES) * sizeof(float);
    hipMemsetAsync(d_ws, 0, zero_bytes, stream);

    // Scatter: E*32 threads.
    long long total_t = (long long)N_EDGES * 32;
    int blocks = (int)((total_t + 255) / 256);
    scatter_kernel<<<blocks, 256, 0, stream>>>(x, esrc, edst, eval, h1, deg);

    // Matmul: one block per row.
    mm_kernel<<<N_NODES, 128, 0, stream>>>(x, h1, deg, W, out);
}

// Round 2
// 215.363 us; speedup vs baseline: 7.4004x; 7.4004x over previous
//
#include <hip/hip_runtime.h>
#include <hip/hip_bf16.h>

// GraphSage: h1 = segsum(val * x[dst] -> src) / deg; out = [x, h1norm] @ W
// N=50000, D=128, E=800000, W [256,128] fp32, out [N,128] fp32.

#define N_NODES 50000
#define DIM 128
#define N_EDGES 800000
#define NB_SCAN 196   // ceil(N_NODES/256)

// ---------------------------------------------------------------------------
// CSR build: histogram -> exclusive scan (2-level) -> fill.
// ---------------------------------------------------------------------------
__global__ __launch_bounds__(256) void hist_kernel(
    const int* __restrict__ esrc, int* __restrict__ cnt)
{
    int e = blockIdx.x * 256 + threadIdx.x;
    if (e < N_EDGES) atomicAdd(&cnt[esrc[e]], 1);
}

__global__ __launch_bounds__(256) void scan1_kernel(
    const int* __restrict__ cnt, int* __restrict__ rowoff, int* __restrict__ bsum)
{
    __shared__ int s[256];
    int t = threadIdx.x;
    int i = blockIdx.x * 256 + t;
    int v = (i < N_NODES) ? cnt[i] : 0;
    s[t] = v;
    __syncthreads();
    #pragma unroll
    for (int off = 1; off < 256; off <<= 1) {
        int tmp = (t >= off) ? s[t - off] : 0;
        __syncthreads();
        s[t] += tmp;
        __syncthreads();
    }
    if (i < N_NODES) rowoff[i] = s[t] - v;     // exclusive within block
    if (t == 255) bsum[blockIdx.x] = s[255];   // block total
}

__global__ __launch_bounds__(256) void scan2_kernel(int* __restrict__ bsum)
{
    __shared__ int s[256];
    int t = threadIdx.x;
    int v = (t < NB_SCAN) ? bsum[t] : 0;
    s[t] = v;
    __syncthreads();
    #pragma unroll
    for (int off = 1; off < 256; off <<= 1) {
        int tmp = (t >= off) ? s[t - off] : 0;
        __syncthreads();
        s[t] += tmp;
        __syncthreads();
    }
    if (t < NB_SCAN) bsum[t] = s[t] - v;       // exclusive block offsets
}

__global__ __launch_bounds__(256) void scan3_kernel(
    int* __restrict__ rowoff, const int* __restrict__ bsum)
{
    int i = blockIdx.x * 256 + threadIdx.x;
    if (i < N_NODES) rowoff[i] += bsum[blockIdx.x];
}

// fill: after this kernel, rowoff[i] has been advanced to the row END.
__global__ __launch_bounds__(256) void fill_kernel(
    const int* __restrict__ esrc, const int* __restrict__ edst,
    const float* __restrict__ eval,
    int* __restrict__ rowoff, int* __restrict__ csr_dst, float* __restrict__ csr_val)
{
    int e = blockIdx.x * 256 + threadIdx.x;
    if (e >= N_EDGES) return;
    int s = esrc[e];
    int p = atomicAdd(&rowoff[s], 1);
    csr_dst[p] = edst[e];
    csr_val[p] = eval[e];
}

// ---------------------------------------------------------------------------
// Gather: one 64-lane wave per node. rowoff[i] is row END (post-fill);
// start = end - cnt[i]. Writes NORMALIZED h1 row once (no atomics).
// ---------------------------------------------------------------------------
__global__ __launch_bounds__(256) void gather_kernel(
    const float* __restrict__ x,
    const int* __restrict__ csr_dst, const float* __restrict__ csr_val,
    const int* __restrict__ rowoff, const int* __restrict__ cnt,
    float* __restrict__ h1)
{
    int node = blockIdx.x * 4 + (threadIdx.x >> 6);
    node = __builtin_amdgcn_readfirstlane(node);   // wave-uniform -> s_loads
    int lane = threadIdx.x & 63;

    int end = rowoff[node];
    int c   = cnt[node];
    int p   = end - c;

    float ax = 0.0f, ay = 0.0f, dg = 0.0f;
    for (; p + 1 < end; p += 2) {
        int d0 = csr_dst[p];
        int d1 = csr_dst[p + 1];
        float v0 = csr_val[p];
        float v1 = csr_val[p + 1];
        float2 xa = *reinterpret_cast<const float2*>(x + (size_t)d0 * DIM + lane * 2);
        float2 xb = *reinterpret_cast<const float2*>(x + (size_t)d1 * DIM + lane * 2);
        ax += v0 * xa.x + v1 * xb.x;
        ay += v0 * xa.y + v1 * xb.y;
        dg += v0 + v1;
    }
    if (p < end) {
        int d0 = csr_dst[p];
        float v0 = csr_val[p];
        float2 xa = *reinterpret_cast<const float2*>(x + (size_t)d0 * DIM + lane * 2);
        ax += v0 * xa.x;
        ay += v0 * xa.y;
        dg += v0;
    }
    float inv = 1.0f / (dg + 1e-6f);
    float2 o; o.x = ax * inv; o.y = ay * inv;
    *reinterpret_cast<float2*>(h1 + (size_t)node * DIM + lane * 2) = o;
}

// ---------------------------------------------------------------------------
// Fallback path (ws too small): atomic scatter + normalize.
// ---------------------------------------------------------------------------
__global__ __launch_bounds__(256) void scatter_kernel(
    const float* __restrict__ x,
    const int* __restrict__ esrc, const int* __restrict__ edst,
    const float* __restrict__ eval,
    float* __restrict__ h1, float* __restrict__ deg)
{
    long long t = (long long)blockIdx.x * blockDim.x + threadIdx.x;
    int e = (int)(t >> 5);
    if (e >= N_EDGES) return;
    int dq = ((int)t & 31) << 2;
    int src = esrc[e];
    int dst = edst[e];
    float v = eval[e];
    const float4 xv = *reinterpret_cast<const float4*>(x + (long long)dst * DIM + dq);
    float* hrow = h1 + (long long)src * DIM + dq;
    atomicAdd(hrow + 0, v * xv.x);
    atomicAdd(hrow + 1, v * xv.y);
    atomicAdd(hrow + 2, v * xv.z);
    atomicAdd(hrow + 3, v * xv.w);
    if ((t & 31) == 0) atomicAdd(deg + src, v);
}

__global__ __launch_bounds__(256) void norm_kernel(
    float* __restrict__ h1, const float* __restrict__ deg)
{
    int i = blockIdx.x;            // node
    int j = threadIdx.x;           // 2 features per thread via float2? keep simple: 128 thr? 256
    // 256 threads: 2 nodes per block
    int node = blockIdx.x * 2 + (threadIdx.x >> 7);
    int f = threadIdx.x & 127;
    if (node >= N_NODES) return;
    float inv = 1.0f / (deg[node] + 1e-6f);
    h1[(size_t)node * DIM + f] *= inv;
    (void)i; (void)j;
}

// ---------------------------------------------------------------------------
// Tiled GEMM: out[N,128] = [x | h1norm] @ W.  Block: 64 rows x 128 cols.
// K=256 in 4 tiles of 64. A staged transposed in LDS [64][68]; B [64][128].
// Thread micro-tile 8 rows x 4 cols -> LDS:FMA issue ratio 3:32.
// ---------------------------------------------------------------------------
__global__ __launch_bounds__(256) void mm_kernel2(
    const float* __restrict__ x, const float* __restrict__ h1,
    const float* __restrict__ W, float* __restrict__ out)
{
    __shared__ float As[64][68];
    __shared__ float Bs[64][128];

    int t  = threadIdx.x;
    int tc = t & 31;          // 32 col-groups
    int tr = t >> 5;          // 8 row-groups
    int j0 = tc * 4;
    int r0 = tr * 8;
    int R0 = blockIdx.x * 64;

    float facc[8][4];
    #pragma unroll
    for (int a = 0; a < 8; ++a)
        #pragma unroll
        for (int b = 0; b < 4; ++b) facc[a][b] = 0.0f;

    int m = t & 63;
    int q = t >> 6;           // 0..3
    int row = R0 + m;
    if (row >= N_NODES) row = N_NODES - 1;   // clamp loads; stores guarded

    for (int kt = 0; kt < 4; ++kt) {
        int k0 = kt * 64;
        const float* S = (kt < 2) ? x : h1;
        int c0 = (kt < 2) ? k0 : (k0 - 128);

        // stage A transposed: As[k][m] = S[row][c0+k]
        #pragma unroll
        for (int i = 0; i < 4; ++i) {
            int c = q * 16 + i * 4;
            const float4 v = *reinterpret_cast<const float4*>(
                S + (size_t)row * DIM + c0 + c);
            As[c + 0][m] = v.x;
            As[c + 1][m] = v.y;
            As[c + 2][m] = v.z;
            As[c + 3][m] = v.w;
        }
        // stage B: Bs[k][j] = W[k0+k][j]
        #pragma unroll
        for (int i = 0; i < 8; ++i) {
            int f  = i * 256 + t;
            int kk = f >> 5;
            int jq = f & 31;
            *reinterpret_cast<float4*>(&Bs[kk][jq * 4]) =
                *reinterpret_cast<const float4*>(W + (size_t)(k0 + kk) * DIM + jq * 4);
        }
        __syncthreads();

        #pragma unroll 8
        for (int kk = 0; kk < 64; ++kk) {
            float4 bv4 = *reinterpret_cast<const float4*>(&Bs[kk][j0]);
            float4 a04 = *reinterpret_cast<const float4*>(&As[kk][r0]);
            float4 a14 = *reinterpret_cast<const float4*>(&As[kk][r0 + 4]);
            float av[8] = {a04.x, a04.y, a04.z, a04.w, a14.x, a14.y, a14.z, a14.w};
            float bv[4] = {bv4.x, bv4.y, bv4.z, bv4.w};
            #pragma unroll
            for (int ri = 0; ri < 8; ++ri)
                #pragma unroll
                for (int ci = 0; ci < 4; ++ci)
                    facc[ri][ci] += av[ri] * bv[ci];
        }
        __syncthreads();
    }

    #pragma unroll
    for (int ri = 0; ri < 8; ++ri) {
        int r = R0 + r0 + ri;
        if (r < N_NODES) {
            float4 o; o.x = facc[ri][0]; o.y = facc[ri][1];
            o.z = facc[ri][2]; o.w = facc[ri][3];
            *reinterpret_cast<float4*>(out + (size_t)r * DIM + j0) = o;
        }
    }
}

extern "C" void kernel_launch(void* const* d_in, const int* in_sizes, int n_in,
                              void* d_out, int out_size, void* d_ws, size_t ws_size,
                              hipStream_t stream) {
    const float* x    = (const float*)d_in[0];
    const float* W    = (const float*)d_in[1];
    const int*   esrc = (const int*)d_in[2];
    const int*   edst = (const int*)d_in[3];
    const float* eval = (const float*)d_in[4];
    float* out = (float*)d_out;

    // ws layout (4B elements):
    //   h1      : N*DIM floats (normalized)
    //   cnt     : N ints
    //   rowoff  : N ints
    //   bsum    : 256 ints
    //   csr_dst : E ints
    //   csr_val : E floats
    float* h1 = (float*)d_ws;
    int*   cnt     = (int*)(h1 + (size_t)N_NODES * DIM);
    int*   rowoff  = cnt + N_NODES;
    int*   bsum    = rowoff + N_NODES;
    int*   csr_dst = bsum + 256;
    float* csr_val = (float*)(csr_dst + N_EDGES);
    size_t needed = ((size_t)N_NODES * DIM + 2 * (size_t)N_NODES + 256
                     + 2 * (size_t)N_EDGES) * 4;

    const int EB = (N_EDGES + 255) / 256;   // 3125

    if (ws_size >= needed) {
        hipMemsetAsync(cnt, 0, (size_t)N_NODES * sizeof(int), stream);
        hist_kernel <<<EB, 256, 0, stream>>>(esrc, cnt);
        scan1_kernel<<<NB_SCAN, 256, 0, stream>>>(cnt, rowoff, bsum);
        scan2_kernel<<<1, 256, 0, stream>>>(bsum);
        scan3_kernel<<<NB_SCAN, 256, 0, stream>>>(rowoff, bsum);
        fill_kernel <<<EB, 256, 0, stream>>>(esrc, edst, eval, rowoff, csr_dst, csr_val);
        gather_kernel<<<N_NODES / 4, 256, 0, stream>>>(x, csr_dst, csr_val,
                                                       rowoff, cnt, h1);
    } else {
        // Fallback: atomic scatter + normalize (needs N*DIM + N floats)
        float* deg = h1 + (size_t)N_NODES * DIM;
        hipMemsetAsync(d_ws, 0,
                       ((size_t)N_NODES * DIM + N_NODES) * sizeof(float), stream);
        long long total_t = (long long)N_EDGES * 32;
        int blocks = (int)((total_t + 255) / 256);
        scatter_kernel<<<blocks, 256, 0, stream>>>(x, esrc, edst, eval, h1, deg);
        norm_kernel<<<(N_NODES + 1) / 2, 256, 0, stream>>>(h1, deg);
    }

    mm_kernel2<<<(N_NODES + 63) / 64, 256, 0, stream>>>(x, h1, W, out);
}

// Round 3
// 178.722 us; speedup vs baseline: 8.9177x; 1.2050x over previous
//
#include <hip/hip_runtime.h>
#include <hip/hip_bf16.h>

// GraphSage: h1 = segsum(val * x[dst] -> src) / deg; out = [x, h1norm] @ W
// N=50000, D=128, E=800000, W [256,128] fp32, out [N,128] fp32.
// Strategy: CSR build (hist/scan/fill) -> bf16 gather -> bf16 MFMA GEMM.

#define N_NODES 50000
#define DIM 128
#define N_EDGES 800000
#define NB_SCAN 196   // ceil(N_NODES/256)

typedef __attribute__((ext_vector_type(8))) short bf16x8;
typedef __attribute__((ext_vector_type(4))) float f32x4;

// round-to-nearest-even f32 -> bf16 bits
__device__ __forceinline__ unsigned short f2bf(float f) {
    unsigned int u = __float_as_uint(f);
    unsigned int r = (u + 0x7FFFu + ((u >> 16) & 1u)) >> 16;
    return (unsigned short)r;
}
__device__ __forceinline__ float bf_lo(unsigned int u) {  // low bf16 -> f32
    return __uint_as_float(u << 16);
}
__device__ __forceinline__ float bf_hi(unsigned int u) {  // high bf16 -> f32
    return __uint_as_float(u & 0xFFFF0000u);
}

// ---------------------------------------------------------------------------
// x [N,128] f32 -> xh [N,128] bf16
// ---------------------------------------------------------------------------
__global__ __launch_bounds__(256) void xconv_kernel(
    const float* __restrict__ x, unsigned short* __restrict__ xh)
{
    int i = blockIdx.x * 256 + threadIdx.x;       // one float4 per thread
    if (i >= N_NODES * DIM / 4) return;
    float4 v = reinterpret_cast<const float4*>(x)[i];
    ushort4 o;
    o.x = f2bf(v.x); o.y = f2bf(v.y); o.z = f2bf(v.z); o.w = f2bf(v.w);
    reinterpret_cast<ushort4*>(xh)[i] = o;
}

// ---------------------------------------------------------------------------
// W [256,128] f32 -> Wfrag in MFMA B-fragment order:
// Wfrag[((nt*8+ks)*64 + l)*8 + j] = bf16(W[ks*32 + (l>>4)*8 + j][nt*16 + (l&15)])
// ---------------------------------------------------------------------------
__global__ __launch_bounds__(256) void wconv_kernel(
    const float* __restrict__ W, unsigned short* __restrict__ wfrag)
{
    int idx = blockIdx.x * 256 + threadIdx.x;    // 0..4095
    if (idx >= 4096) return;
    int l  = idx & 63;
    int ks = (idx >> 6) & 7;
    int nt = idx >> 9;
    int col  = nt * 16 + (l & 15);
    int krow = ks * 32 + (l >> 4) * 8;
    ushort4 lo, hi;
    lo.x = f2bf(W[(krow + 0) * DIM + col]);
    lo.y = f2bf(W[(krow + 1) * DIM + col]);
    lo.z = f2bf(W[(krow + 2) * DIM + col]);
    lo.w = f2bf(W[(krow + 3) * DIM + col]);
    hi.x = f2bf(W[(krow + 4) * DIM + col]);
    hi.y = f2bf(W[(krow + 5) * DIM + col]);
    hi.z = f2bf(W[(krow + 6) * DIM + col]);
    hi.w = f2bf(W[(krow + 7) * DIM + col]);
    reinterpret_cast<ushort4*>(wfrag)[idx * 2 + 0] = lo;
    reinterpret_cast<ushort4*>(wfrag)[idx * 2 + 1] = hi;
}

// ---------------------------------------------------------------------------
// CSR build: histogram -> exclusive scan (2-level) -> fill.
// ---------------------------------------------------------------------------
__global__ __launch_bounds__(256) void hist_kernel(
    const int* __restrict__ esrc, int* __restrict__ cnt)
{
    int e = blockIdx.x * 256 + threadIdx.x;
    if (e < N_EDGES) atomicAdd(&cnt[esrc[e]], 1);
}

__global__ __launch_bounds__(256) void scan1_kernel(
    const int* __restrict__ cnt, int* __restrict__ rowoff, int* __restrict__ bsum)
{
    __shared__ int s[256];
    int t = threadIdx.x;
    int i = blockIdx.x * 256 + t;
    int v = (i < N_NODES) ? cnt[i] : 0;
    s[t] = v;
    __syncthreads();
    #pragma unroll
    for (int off = 1; off < 256; off <<= 1) {
        int tmp = (t >= off) ? s[t - off] : 0;
        __syncthreads();
        s[t] += tmp;
        __syncthreads();
    }
    if (i < N_NODES) rowoff[i] = s[t] - v;
    if (t == 255) bsum[blockIdx.x] = s[255];
}

__global__ __launch_bounds__(256) void scan2_kernel(int* __restrict__ bsum)
{
    __shared__ int s[256];
    int t = threadIdx.x;
    int v = (t < NB_SCAN) ? bsum[t] : 0;
    s[t] = v;
    __syncthreads();
    #pragma unroll
    for (int off = 1; off < 256; off <<= 1) {
        int tmp = (t >= off) ? s[t - off] : 0;
        __syncthreads();
        s[t] += tmp;
        __syncthreads();
    }
    if (t < NB_SCAN) bsum[t] = s[t] - v;
}

__global__ __launch_bounds__(256) void scan3_kernel(
    int* __restrict__ rowoff, const int* __restrict__ bsum)
{
    int i = blockIdx.x * 256 + threadIdx.x;
    if (i < N_NODES) rowoff[i] += bsum[blockIdx.x];
}

// After fill, rowoff[i] == end of row i == start of row i+1.
__global__ __launch_bounds__(256) void fill_kernel(
    const int* __restrict__ esrc, const int* __restrict__ edst,
    const float* __restrict__ eval,
    int* __restrict__ rowoff, int* __restrict__ csr_dst, float* __restrict__ csr_val)
{
    int e = blockIdx.x * 256 + threadIdx.x;
    if (e >= N_EDGES) return;
    int s = esrc[e];
    int p = atomicAdd(&rowoff[s], 1);
    csr_dst[p] = edst[e];
    csr_val[p] = eval[e];
}

// ---------------------------------------------------------------------------
// Gather: one wave per node; reads bf16 x rows; writes normalized bf16 h1 row.
// Post-fill: start = rowoff[node-1] (0 for node 0), end = rowoff[node].
// ---------------------------------------------------------------------------
__global__ __launch_bounds__(256) void gather_kernel(
    const unsigned short* __restrict__ xh,
    const int* __restrict__ csr_dst, const float* __restrict__ csr_val,
    const int* __restrict__ rowoff,
    unsigned short* __restrict__ h1h)
{
    int node = blockIdx.x * 4 + (threadIdx.x >> 6);
    node = __builtin_amdgcn_readfirstlane(node);
    int lane = threadIdx.x & 63;

    int end = rowoff[node];
    int p   = (node == 0) ? 0 : rowoff[node - 1];

    const unsigned int* xu = reinterpret_cast<const unsigned int*>(xh);

    float ax = 0.0f, ay = 0.0f, dg = 0.0f;
    for (; p + 1 < end; p += 2) {
        int d0 = csr_dst[p];
        int d1 = csr_dst[p + 1];
        float v0 = csr_val[p];
        float v1 = csr_val[p + 1];
        unsigned int ua = xu[d0 * 64 + lane];
        unsigned int ub = xu[d1 * 64 + lane];
        ax += v0 * bf_lo(ua) + v1 * bf_lo(ub);
        ay += v0 * bf_hi(ua) + v1 * bf_hi(ub);
        dg += v0 + v1;
    }
    if (p < end) {
        int d0 = csr_dst[p];
        float v0 = csr_val[p];
        unsigned int ua = xu[d0 * 64 + lane];
        ax += v0 * bf_lo(ua);
        ay += v0 * bf_hi(ua);
        dg += v0;
    }
    float inv = 1.0f / (dg + 1e-6f);
    unsigned int o = ((unsigned int)f2bf(ay * inv) << 16) | f2bf(ax * inv);
    reinterpret_cast<unsigned int*>(h1h)[node * 64 + lane] = o;
}

// ---------------------------------------------------------------------------
// MFMA GEMM: out[N,128] = [xh | h1h] @ W  (bf16 inputs, fp32 accum/output).
// Block = 4 waves, tile 64 rows x 128 cols; wave w covers cols [w*32, w*32+32).
// No LDS, no barriers. A frags from global (L1/L2-cached), B from Wfrag.
// ---------------------------------------------------------------------------
__global__ __launch_bounds__(256) void gemm_kernel(
    const unsigned short* __restrict__ xh,
    const unsigned short* __restrict__ h1h,
    const unsigned short* __restrict__ wfrag,
    float* __restrict__ out)
{
    int l   = threadIdx.x & 63;
    int wid = threadIdx.x >> 6;
    int r0  = blockIdx.x * 64;
    int lr  = l & 15;    // row within A-frag / col within B-frag
    int lk  = l >> 4;    // k-group (0..3)

    f32x4 acc[4][2];
    #pragma unroll
    for (int mf = 0; mf < 4; ++mf)
        #pragma unroll
        for (int nf = 0; nf < 2; ++nf)
            acc[mf][nf] = (f32x4){0.f, 0.f, 0.f, 0.f};

    #pragma unroll
    for (int ks = 0; ks < 8; ++ks) {
        const unsigned short* src = (ks < 4) ? xh : h1h;
        int coff = (ks & 3) * 32 + lk * 8;    // element offset within row

        bf16x8 a[4];
        #pragma unroll
        for (int mf = 0; mf < 4; ++mf) {
            int row = r0 + mf * 16 + lr;
            if (row >= N_NODES) row = N_NODES - 1;   // stores guarded below
            a[mf] = *reinterpret_cast<const bf16x8*>(src + (size_t)row * DIM + coff);
        }
        bf16x8 b[2];
        #pragma unroll
        for (int nf = 0; nf < 2; ++nf) {
            int nt = wid * 2 + nf;
            b[nf] = *reinterpret_cast<const bf16x8*>(
                wfrag + ((size_t)((nt * 8 + ks) * 64 + l)) * 8);
        }
        #pragma unroll
        for (int mf = 0; mf < 4; ++mf)
            #pragma unroll
            for (int nf = 0; nf < 2; ++nf)
                acc[mf][nf] = __builtin_amdgcn_mfma_f32_16x16x32_bf16(
                    a[mf], b[nf], acc[mf][nf], 0, 0, 0);
    }

    // Epilogue: D[row=(l>>4)*4+rr][col=l&15] per 16x16 frag.
    #pragma unroll
    for (int mf = 0; mf < 4; ++mf) {
        #pragma unroll
        for (int nf = 0; nf < 2; ++nf) {
            int col = wid * 32 + nf * 16 + lr;
            #pragma unroll
            for (int rr = 0; rr < 4; ++rr) {
                int row = r0 + mf * 16 + lk * 4 + rr;
                if (row < N_NODES)
                    out[(size_t)row * DIM + col] = acc[mf][nf][rr];
            }
        }
    }
}

extern "C" void kernel_launch(void* const* d_in, const int* in_sizes, int n_in,
                              void* d_out, int out_size, void* d_ws, size_t ws_size,
                              hipStream_t stream) {
    const float* x    = (const float*)d_in[0];
    const float* W    = (const float*)d_in[1];
    const int*   esrc = (const int*)d_in[2];
    const int*   edst = (const int*)d_in[3];
    const float* eval = (const float*)d_in[4];
    float* out = (float*)d_out;

    // ws layout (total 32,401,024 B):
    //   xh      : N*DIM bf16 (12.8 MB)
    //   h1h     : N*DIM bf16 (12.8 MB)
    //   cnt     : N ints (200 KB)  -- reused as Wfrag (64 KB) after scan1
    //   rowoff  : N ints
    //   bsum    : 256 ints
    //   csr_dst : E ints
    //   csr_val : E floats
    unsigned short* xh  = (unsigned short*)d_ws;
    unsigned short* h1h = xh + (size_t)N_NODES * DIM;
    int*   cnt     = (int*)(h1h + (size_t)N_NODES * DIM);
    int*   rowoff  = cnt + N_NODES;
    int*   bsum    = rowoff + N_NODES;
    int*   csr_dst = bsum + 256;
    float* csr_val = (float*)(csr_dst + N_EDGES);
    unsigned short* wfrag = (unsigned short*)cnt;   // alias: cnt dead after scan1

    const int EB = (N_EDGES + 255) / 256;           // 3125
    const int XB = (N_NODES * DIM / 4 + 255) / 256; // 6250

    hipMemsetAsync(cnt, 0, (size_t)N_NODES * sizeof(int), stream);
    xconv_kernel<<<XB, 256, 0, stream>>>(x, xh);
    hist_kernel <<<EB, 256, 0, stream>>>(esrc, cnt);
    scan1_kernel<<<NB_SCAN, 256, 0, stream>>>(cnt, rowoff, bsum);
    scan2_kernel<<<1, 256, 0, stream>>>(bsum);
    scan3_kernel<<<NB_SCAN, 256, 0, stream>>>(rowoff, bsum);
    wconv_kernel<<<16, 256, 0, stream>>>(W, wfrag);   // overwrites cnt (dead)
    fill_kernel <<<EB, 256, 0, stream>>>(esrc, edst, eval, rowoff, csr_dst, csr_val);
    gather_kernel<<<N_NODES / 4, 256, 0, stream>>>(xh, csr_dst, csr_val, rowoff, h1h);
    gemm_kernel<<<(N_NODES + 63) / 64, 256, 0, stream>>>(xh, h1h, wfrag, out);
}

// Round 4
// 163.406 us; speedup vs baseline: 9.7535x; 1.0937x over previous
//
#include <hip/hip_runtime.h>
#include <hip/hip_bf16.h>

// GraphSage: h1 = segsum(val * x[dst] -> src) / deg; out = [x, h1norm] @ W
// N=50000, D=128, E=800000, W [256,128] fp32, out [N,128] fp32.
// Pipeline: xconv+hist -> scan1 -> scan2+wconv -> scan3 -> fill(packed int2)
//           -> bf16 gather -> bf16 MFMA GEMM.

#define N_NODES 50000
#define DIM 128
#define N_EDGES 800000
#define NB_SCAN 196   // ceil(N_NODES/256)
#define EB 3125       // ceil(N_EDGES/256)
#define XB 6250       // N_NODES*DIM/4/256

typedef __attribute__((ext_vector_type(8))) short bf16x8;
typedef __attribute__((ext_vector_type(4))) float f32x4;

// round-to-nearest-even f32 -> bf16 bits
__device__ __forceinline__ unsigned short f2bf(float f) {
    unsigned int u = __float_as_uint(f);
    unsigned int r = (u + 0x7FFFu + ((u >> 16) & 1u)) >> 16;
    return (unsigned short)r;
}
__device__ __forceinline__ float bf_lo(unsigned int u) {
    return __uint_as_float(u << 16);
}
__device__ __forceinline__ float bf_hi(unsigned int u) {
    return __uint_as_float(u & 0xFFFF0000u);
}

// ---------------------------------------------------------------------------
// Fused: x f32 -> bf16 convert  +  edge-source histogram.
// ---------------------------------------------------------------------------
__global__ __launch_bounds__(256) void xconv_hist_kernel(
    const float* __restrict__ x, unsigned short* __restrict__ xh,
    const int* __restrict__ esrc, int* __restrict__ cnt)
{
    int i = blockIdx.x * 256 + threadIdx.x;
    if (i < N_NODES * DIM / 4) {
        float4 v = reinterpret_cast<const float4*>(x)[i];
        ushort4 o;
        o.x = f2bf(v.x); o.y = f2bf(v.y); o.z = f2bf(v.z); o.w = f2bf(v.w);
        reinterpret_cast<ushort4*>(xh)[i] = o;
    }
    if (blockIdx.x < EB) {
        int e = blockIdx.x * 256 + threadIdx.x;
        if (e < N_EDGES) atomicAdd(&cnt[esrc[e]], 1);
    }
}

// ---------------------------------------------------------------------------
// Scan level 1: per-block exclusive scan of cnt -> rowoff, block totals -> bsum
// ---------------------------------------------------------------------------
__global__ __launch_bounds__(256) void scan1_kernel(
    const int* __restrict__ cnt, int* __restrict__ rowoff, int* __restrict__ bsum)
{
    __shared__ int s[256];
    int t = threadIdx.x;
    int i = blockIdx.x * 256 + t;
    int v = (i < N_NODES) ? cnt[i] : 0;
    s[t] = v;
    __syncthreads();
    #pragma unroll
    for (int off = 1; off < 256; off <<= 1) {
        int tmp = (t >= off) ? s[t - off] : 0;
        __syncthreads();
        s[t] += tmp;
        __syncthreads();
    }
    if (i < N_NODES) rowoff[i] = s[t] - v;
    if (t == 255) bsum[blockIdx.x] = s[255];
}

// ---------------------------------------------------------------------------
// Fused: block 0 scans bsum; blocks 1..16 pack W into MFMA B-fragment order:
// Wfrag[((nt*8+ks)*64 + l)*8 + j] = bf16(W[ks*32 + (l>>4)*8 + j][nt*16+(l&15)])
// (wfrag aliases cnt -- cnt is dead after scan1.)
// ---------------------------------------------------------------------------
__global__ __launch_bounds__(256) void scan2_wconv_kernel(
    int* __restrict__ bsum, const float* __restrict__ W,
    unsigned short* __restrict__ wfrag)
{
    if (blockIdx.x == 0) {
        __shared__ int s[256];
        int t = threadIdx.x;
        int v = (t < NB_SCAN) ? bsum[t] : 0;
        s[t] = v;
        __syncthreads();
        #pragma unroll
        for (int off = 1; off < 256; off <<= 1) {
            int tmp = (t >= off) ? s[t - off] : 0;
            __syncthreads();
            s[t] += tmp;
            __syncthreads();
        }
        if (t < NB_SCAN) bsum[t] = s[t] - v;
    } else {
        int idx = (blockIdx.x - 1) * 256 + threadIdx.x;   // 0..4095
        int l  = idx & 63;
        int ks = (idx >> 6) & 7;
        int nt = idx >> 9;
        int col  = nt * 16 + (l & 15);
        int krow = ks * 32 + (l >> 4) * 8;
        ushort4 lo, hi;
        lo.x = f2bf(W[(krow + 0) * DIM + col]);
        lo.y = f2bf(W[(krow + 1) * DIM + col]);
        lo.z = f2bf(W[(krow + 2) * DIM + col]);
        lo.w = f2bf(W[(krow + 3) * DIM + col]);
        hi.x = f2bf(W[(krow + 4) * DIM + col]);
        hi.y = f2bf(W[(krow + 5) * DIM + col]);
        hi.z = f2bf(W[(krow + 6) * DIM + col]);
        hi.w = f2bf(W[(krow + 7) * DIM + col]);
        reinterpret_cast<ushort4*>(wfrag)[idx * 2 + 0] = lo;
        reinterpret_cast<ushort4*>(wfrag)[idx * 2 + 1] = hi;
    }
}

__global__ __launch_bounds__(256) void scan3_kernel(
    int* __restrict__ rowoff, const int* __restrict__ bsum)
{
    int i = blockIdx.x * 256 + threadIdx.x;
    if (i < N_NODES) rowoff[i] += bsum[blockIdx.x];
}

// ---------------------------------------------------------------------------
// Fill: one packed 8B scatter per edge (int2{dst, val_bits}).
// After fill, rowoff[i] == end of row i.
// ---------------------------------------------------------------------------
__global__ __launch_bounds__(256) void fill_kernel(
    const int* __restrict__ esrc, const int* __restrict__ edst,
    const float* __restrict__ eval,
    int* __restrict__ rowoff, int2* __restrict__ csr)
{
    int e = blockIdx.x * 256 + threadIdx.x;
    if (e >= N_EDGES) return;
    int s = esrc[e];
    int p = atomicAdd(&rowoff[s], 1);
    int2 pk;
    pk.x = edst[e];
    pk.y = __float_as_int(eval[e]);
    csr[p] = pk;
}

// ---------------------------------------------------------------------------
// Gather: one wave per node; scalar csr loads; bf16 x-row gathers.
// start = rowoff[node-1] (0 for node 0), end = rowoff[node].
// ---------------------------------------------------------------------------
__global__ __launch_bounds__(256) void gather_kernel(
    const unsigned short* __restrict__ xh,
    const int2* __restrict__ csr,
    const int* __restrict__ rowoff,
    unsigned short* __restrict__ h1h)
{
    int node = blockIdx.x * 4 + (threadIdx.x >> 6);
    node = __builtin_amdgcn_readfirstlane(node);
    int lane = threadIdx.x & 63;

    int end = rowoff[node];
    int p   = (node == 0) ? 0 : rowoff[node - 1];

    const unsigned int* xu = reinterpret_cast<const unsigned int*>(xh);

    float ax = 0.0f, ay = 0.0f, dg = 0.0f;
    for (; p + 1 < end; p += 2) {
        int2 e0 = csr[p];
        int2 e1 = csr[p + 1];
        float v0 = __int_as_float(e0.y);
        float v1 = __int_as_float(e1.y);
        unsigned int ua = xu[e0.x * 64 + lane];
        unsigned int ub = xu[e1.x * 64 + lane];
        ax += v0 * bf_lo(ua) + v1 * bf_lo(ub);
        ay += v0 * bf_hi(ua) + v1 * bf_hi(ub);
        dg += v0 + v1;
    }
    if (p < end) {
        int2 e0 = csr[p];
        float v0 = __int_as_float(e0.y);
        unsigned int ua = xu[e0.x * 64 + lane];
        ax += v0 * bf_lo(ua);
        ay += v0 * bf_hi(ua);
        dg += v0;
    }
    float inv = 1.0f / (dg + 1e-6f);
    unsigned int o = ((unsigned int)f2bf(ay * inv) << 16) | f2bf(ax * inv);
    reinterpret_cast<unsigned int*>(h1h)[node * 64 + lane] = o;
}

// ---------------------------------------------------------------------------
// MFMA GEMM: out[N,128] = [xh | h1h] @ W (bf16 in, fp32 out).
// Block = 4 waves, tile 64 rows x 128 cols; wave w covers cols [w*32,w*32+32).
// No LDS, no barriers.
// ---------------------------------------------------------------------------
__global__ __launch_bounds__(256) void gemm_kernel(
    const unsigned short* __restrict__ xh,
    const unsigned short* __restrict__ h1h,
    const unsigned short* __restrict__ wfrag,
    float* __restrict__ out)
{
    int l   = threadIdx.x & 63;
    int wid = threadIdx.x >> 6;
    int r0  = blockIdx.x * 64;
    int lr  = l & 15;
    int lk  = l >> 4;

    f32x4 acc[4][2];
    #pragma unroll
    for (int mf = 0; mf < 4; ++mf)
        #pragma unroll
        for (int nf = 0; nf < 2; ++nf)
            acc[mf][nf] = (f32x4){0.f, 0.f, 0.f, 0.f};

    #pragma unroll
    for (int ks = 0; ks < 8; ++ks) {
        const unsigned short* src = (ks < 4) ? xh : h1h;
        int coff = (ks & 3) * 32 + lk * 8;

        bf16x8 a[4];
        #pragma unroll
        for (int mf = 0; mf < 4; ++mf) {
            int row = r0 + mf * 16 + lr;
            if (row >= N_NODES) row = N_NODES - 1;
            a[mf] = *reinterpret_cast<const bf16x8*>(src + (size_t)row * DIM + coff);
        }
        bf16x8 b[2];
        #pragma unroll
        for (int nf = 0; nf < 2; ++nf) {
            int nt = wid * 2 + nf;
            b[nf] = *reinterpret_cast<const bf16x8*>(
                wfrag + ((size_t)((nt * 8 + ks) * 64 + l)) * 8);
        }
        #pragma unroll
        for (int mf = 0; mf < 4; ++mf)
            #pragma unroll
            for (int nf = 0; nf < 2; ++nf)
                acc[mf][nf] = __builtin_amdgcn_mfma_f32_16x16x32_bf16(
                    a[mf], b[nf], acc[mf][nf], 0, 0, 0);
    }

    #pragma unroll
    for (int mf = 0; mf < 4; ++mf) {
        #pragma unroll
        for (int nf = 0; nf < 2; ++nf) {
            int col = wid * 32 + nf * 16 + lr;
            #pragma unroll
            for (int rr = 0; rr < 4; ++rr) {
                int row = r0 + mf * 16 + lk * 4 + rr;
                if (row < N_NODES)
                    out[(size_t)row * DIM + col] = acc[mf][nf][rr];
            }
        }
    }
}

extern "C" void kernel_launch(void* const* d_in, const int* in_sizes, int n_in,
                              void* d_out, int out_size, void* d_ws, size_t ws_size,
                              hipStream_t stream) {
    const float* x    = (const float*)d_in[0];
    const float* W    = (const float*)d_in[1];
    const int*   esrc = (const int*)d_in[2];
    const int*   edst = (const int*)d_in[3];
    const float* eval = (const float*)d_in[4];
    float* out = (float*)d_out;

    // ws layout (32.4 MB):
    //   xh     : N*DIM bf16 (12.8 MB)
    //   h1h    : N*DIM bf16 (12.8 MB)
    //   cnt    : N ints  (aliased by wfrag, 64 KB, after scan1)
    //   rowoff : N ints
    //   bsum   : 256 ints
    //   csr    : E int2 (6.4 MB)
    unsigned short* xh  = (unsigned short*)d_ws;
    unsigned short* h1h = xh + (size_t)N_NODES * DIM;
    int*  cnt    = (int*)(h1h + (size_t)N_NODES * DIM);
    int*  rowoff = cnt + N_NODES;
    int*  bsum   = rowoff + N_NODES;
    int2* csr    = (int2*)(bsum + 256);
    unsigned short* wfrag = (unsigned short*)cnt;

    hipMemsetAsync(cnt, 0, (size_t)N_NODES * sizeof(int), stream);
    xconv_hist_kernel<<<XB, 256, 0, stream>>>(x, xh, esrc, cnt);
    scan1_kernel<<<NB_SCAN, 256, 0, stream>>>(cnt, rowoff, bsum);
    scan2_wconv_kernel<<<17, 256, 0, stream>>>(bsum, W, wfrag);
    scan3_kernel<<<NB_SCAN, 256, 0, stream>>>(rowoff, bsum);
    fill_kernel<<<EB, 256, 0, stream>>>(esrc, edst, eval, rowoff, csr);
    gather_kernel<<<N_NODES / 4, 256, 0, stream>>>(xh, csr, rowoff, h1h);
    gemm_kernel<<<(N_NODES + 63) / 64, 256, 0, stream>>>(xh, h1h, wfrag, out);
}